// Round 6
// baseline (321.501 us; speedup 1.0000x reference)
//
#include <hip/hip_runtime.h>

// Problem constants (from reference)
#define R_MAX 32
#define S_MAX 2
#define C_Z   128
#define NTB   67                     // 2*R_MAX + 2 + 1
#define IN_DIM 141                   // 2*NTB + (2*S_MAX+2) + 1
#define JT   256                     // j-tile width per block

typedef float vf4 __attribute__((ext_vector_type(4)));

__device__ __forceinline__ int clampi(int x, int lo, int hi) {
    return min(max(x, lo), hi);
}

// Grid: (ceil(N/JT), B*N). Block: 256. One i-row x 256-j tile per block.
// Minimal-overhead streaming: 1 KB LDS (codes only), no table staging,
// hot loop = reg-decode + 3 L1 gathers + 1 coalesced float4 store.
__global__ __launch_bounds__(256, 4) void relpos_kernel(
    const int* __restrict__ asym, const int* __restrict__ ent,
    const int* __restrict__ res,  const int* __restrict__ tok,
    const int* __restrict__ sym,  const int* __restrict__ mask,
    const float* __restrict__ W,
    float* __restrict__ out, int N)
{
    __shared__ __align__(16) int codeT[JT];   // transposed: [(j&7)*32 + (j>>3)]

    const int tid = threadIdx.x;
    const int row = blockIdx.y;               // b*N + i
    const int jb  = blockIdx.x * JT;
    const int b   = row / N;
    const vf4* __restrict__ W4 = (const vf4*)W;

    // i-side scalars (wave-uniform -> s_loads)
    const int ai = asym[row], ei = ent[row], ri = res[row], ti = tok[row], si = sym[row];

    // ---- Phase 1: classify this j-tile ----
    {
        int j = jb + tid;
        int code = 0;
        if (j < N) {
            int jrow = b * N + j;
            int aj = asym[jrow], ej = ent[jrow], rj = res[jrow], tj = tok[jrow], sj = sym[jrow];
            bool sc = (ai == aj), sent = (ei == ej), sr = (ri == rj);

            int d_res   = sc ? clampi(ri - rj + R_MAX, 0, 2*R_MAX) : (2*R_MAX + 1);
            int d_tok   = (sc && sr) ? clampi(ti - tj + R_MAX, 0, 2*R_MAX) : (2*R_MAX + 1);
            int d_chain = sent ? clampi(si - sj + S_MAX, 0, 2*S_MAX) : (2*S_MAX + 1);

            if (mask[(long long)row * N + j] != 0) { d_res = 66; d_tok = 66; }

            code = d_res | (d_tok << 7) | (d_chain << 14) | (sent ? (1 << 17) : 0);
        }
        codeT[(tid & 7) * 32 + (tid >> 3)] = code;
    }
    __syncthreads();

    // ---- Phase 2: pure output stream ----
    const int chunk = tid & 31;
    const int psub  = tid >> 5;
    const vf4* __restrict__ Wc = W4 + chunk;

    const vf4 e = Wc[(2 * NTB) * 32];         // w_ent chunk, loop-invariant

    vf4* __restrict__ outp = (vf4*)out + ((long long)row * N + jb) * 32 + chunk;
    const int jmax = min(JT, N - jb);

    int4 creg[8];
    {
        const int4* cp = (const int4*)&codeT[psub * 32];
        #pragma unroll
        for (int k = 0; k < 8; ++k) creg[k] = cp[k];   // 8x ds_read_b128 broadcast
    }

#define PROC(codev, itv)                                                      \
    {                                                                         \
        int code    = (codev);                                                \
        int pair    = (itv) * 8 + psub;                                       \
        int d_res   = code & 127;                                             \
        int d_tok   = (code >> 7) & 127;                                      \
        int d_chain = (code >> 14) & 7;                                       \
        float se    = (float)((code >> 17) & 1);                              \
        vf4 r  = Wc[d_res * 32];                                              \
        vf4 t  = Wc[(NTB + d_tok) * 32];                                      \
        vf4 cc = Wc[(2 * NTB + 1 + d_chain) * 32];                            \
        vf4 o  = r + t + se * e + cc;                                         \
        outp[pair * 32] = o;                                                  \
    }

    if (jmax == JT) {
        #pragma unroll
        for (int k = 0; k < 8; ++k) {
            int4 c = creg[k];
            PROC(c.x, 4*k + 0)
            PROC(c.y, 4*k + 1)
            PROC(c.z, 4*k + 2)
            PROC(c.w, 4*k + 3)
        }
    } else {
        #pragma unroll
        for (int k = 0; k < 8; ++k) {
            int4 c = creg[k];
            if (4*k*8 + psub < jmax)       PROC(c.x, 4*k + 0)
            if ((4*k + 1)*8 + psub < jmax) PROC(c.y, 4*k + 1)
            if ((4*k + 2)*8 + psub < jmax) PROC(c.z, 4*k + 2)
            if ((4*k + 3)*8 + psub < jmax) PROC(c.w, 4*k + 3)
        }
    }
#undef PROC
}

extern "C" void kernel_launch(void* const* d_in, const int* in_sizes, int n_in,
                              void* d_out, int out_size, void* d_ws, size_t ws_size,
                              hipStream_t stream) {
    const int*   asym = (const int*)d_in[0];
    const int*   ent  = (const int*)d_in[1];
    const int*   res  = (const int*)d_in[2];
    const int*   tok  = (const int*)d_in[3];
    const int*   sym  = (const int*)d_in[4];
    const int*   mask = (const int*)d_in[5];
    const float* W    = (const float*)d_in[6];
    float*       out  = (float*)d_out;

    long long BN      = in_sizes[0];        // B*N
    long long mask_sz = in_sizes[5];        // B*N*N
    int N = (int)(mask_sz / BN);

    dim3 grid((unsigned)((N + JT - 1) / JT), (unsigned)BN);
    relpos_kernel<<<grid, 256, 0, stream>>>(
        asym, ent, res, tok, sym, mask, W, out, N);
}